// Round 10
// baseline (335.368 us; speedup 1.0000x reference)
//
#include <hip/hip_runtime.h>

// ---------------------------------------------------------------------------
// MultiQueryAttention: B=4 S=2048 E=1024 H=16 D=64 Q=4
// ref: q=x@Wq^T+bq (per qi), k=x@Wk^T+bk, v=x@Wv^T+bv
//      scores[qi,b,s,h,g] = dot_d(q[h],k[g])/8 ; softmax over g (16 heads!)
//      out[qi,b,s,h,d] = sum_g p*v[g,d]
//      t[b, 128h + s/16, 64(s%16)+d] = sum_qi out   (torch transpose+reshape)
//      final = t @ Wo^T + bo   (fp32 out)
// ---------------------------------------------------------------------------

typedef __bf16 bf16x8 __attribute__((ext_vector_type(8)));
typedef float f32x4 __attribute__((ext_vector_type(4)));
typedef float f32x16 __attribute__((ext_vector_type(16)));

__device__ __forceinline__ unsigned short f2b(float f) {
  unsigned u = __float_as_uint(f);
  return (unsigned short)((u + 0x7fffu + ((u >> 16) & 1u)) >> 16);  // RNE
}

__device__ __forceinline__ void async16(const void* g, void* l) {
  __builtin_amdgcn_global_load_lds(
      (const __attribute__((address_space(1))) void*)g,
      (__attribute__((address_space(3))) void*)l, 16, 0, 0);
}

// ------------------- fused fp32->bf16 convert + bias concat ------------------
__global__ __launch_bounds__(256) void cvt_all(
    const float* __restrict__ x, const float* __restrict__ Wq, const float* __restrict__ Wk,
    const float* __restrict__ Wv, const float* __restrict__ Wo, const float* __restrict__ bq,
    const float* __restrict__ bk, const float* __restrict__ bv,
    unsigned short* __restrict__ xb, unsigned short* __restrict__ wcat,
    unsigned short* __restrict__ wo_b, float* __restrict__ biascat) {
  if (blockIdx.x >= 15360) {
    int j = (blockIdx.x - 15360) * 256 + threadIdx.x;  // 0..6143
    if (j < 6144) {
      float v = (j < 4096) ? bq[j] : (j < 5120 ? bk[j - 4096] : bv[j - 5120]);
      biascat[j] = v;
    }
    return;
  }
  int i = blockIdx.x * 256 + threadIdx.x;
  const float* s;
  unsigned short* d;
  int off;
  if (i < 2097152)      { s = x;  d = xb;             off = i; }
  else if (i < 3145728) { s = Wq; d = wcat;           off = i - 2097152; }
  else if (i < 3407872) { s = Wk; d = wcat + 4194304; off = i - 3145728; }
  else if (i < 3670016) { s = Wv; d = wcat + 5242880; off = i - 3407872; }
  else                  { s = Wo; d = wo_b;           off = i - 3670016; }
  float4 v = ((const float4*)s)[off];
  uint2 o;
  o.x = (unsigned)f2b(v.x) | ((unsigned)f2b(v.y) << 16);
  o.y = (unsigned)f2b(v.z) | ((unsigned)f2b(v.w) << 16);
  ((uint2*)d)[off] = o;
}

// ------------------ 256x256 deep-pipelined GEMM (QKV) -----------------------
// R10: R3 skeleton (verified best: 114-116us, MfmaUtil 39%, 0 conflicts) with
// B-OPERAND DIRECT FROM GLOBAL/L2. Rationale: R3's iter = LDS burst (96
// ds_read_b128 ~1150cy/CU) + MFMA burst (~1030cy) nearly serialized; every
// scheduling-level overlap attempt regressed (R4/R5/R6/R8 ledger). Structural
// fix: B-frags are only 4 reads/wave/iter and the per-block B tile (512KB)
// is L2-resident (same-column blocks land on the same XCD: stride 24 % 8 ==
// 0), so load B straight into registers (compiler-tracked waits) and keep
// only A in LDS. LDS reads 96->64/CU (~770cy), staging loads 4->2/thread.
// Regs: +16 VGPR (B single-buffered); 8 waves x (116 VGPR + 128 acc) fits
// the 2048/SIMD budget -> still 1 block/CU (LDS now 64KB).
//
// PAIR-ROW SWIZZLE for A (0 conflicts measured): granule g (16B) of row r at
// phys p = (2g+(r&1)) ^ ((r>>1)&7) within pair (r>>1). Store: linear LDS
// dest (global_load_lds), pre-swizzled GLOBAL source. Read:
// p = (4ks + 2*lhi + (l31&1)) ^ ((l31>>1)&7).
//
// ONE barrier per K-tile; B loads issued at iter start (compiler inserts
// counted vmcnt before dependent MFMAs); stage A(kt+2) issued AFTER B loads
// so the manual end-of-iter vmcnt(2) retires stageA(kt+1) (+ any B) and
// keeps stageA(kt+2) in flight.
__global__ __launch_bounds__(512, 2) void gemm256(
    const unsigned short* __restrict__ A, const unsigned short* __restrict__ Bt,
    const float* __restrict__ bias, unsigned short* __restrict__ C,
    int M, int N, int K) {
  __shared__ __align__(16) unsigned short As[4][8192];
  const int t = threadIdx.x;
  const int lane = t & 63, w = t >> 6;
  const int l31 = lane & 31, lhi = lane >> 5;
  const int wm = (w >> 2) * 128, wn = (w & 3) * 64;
  const int bm0 = blockIdx.y * 256, bn0 = blockIdx.x * 256;

  // ---- A staging (pair-row pre-swizzled source, linear LDS dest)
  const int p0 = t & 7, pr0 = t >> 3;
  const int u0 = p0 ^ (pr0 & 7);
  const size_t aoff0 = (size_t)(2 * pr0 + (u0 & 1)) * K + (u0 >> 1) * 8;
  const unsigned short* aS0 = A + (size_t)bm0 * K + aoff0;
  const unsigned short* aS1 = aS0 + (size_t)128 * K;
  const int d0 = t * 8, d1 = d0 + 4096;

  // ---- A LDS read offsets
  const int plo = 2 * lhi + (l31 & 1);
  const int pswz = (l31 >> 1) & 7;
  const int pg0 = ((0 + plo) ^ pswz) * 8;
  const int pg1 = ((4 + plo) ^ pswz) * 8;
  int prA[4];
#pragma unroll
  for (int mi = 0; mi < 4; ++mi) prA[mi] = ((wm + mi * 32 + l31) >> 1) * 64;

  // ---- B direct-global per-lane bases: row = bn0+wn+nj*32+l31, col lhi*8
  // (+16 elems for ks=1, +kt*32 per tile)
  const unsigned short* bB0 = Bt + (size_t)(bn0 + wn + l31) * K + lhi * 8;
  const unsigned short* bB1 = Bt + (size_t)(bn0 + wn + 32 + l31) * K + lhi * 8;

  f32x16 acc[4][2];
#pragma unroll
  for (int mi = 0; mi < 4; ++mi)
#pragma unroll
    for (int nj = 0; nj < 2; ++nj)
#pragma unroll
      for (int e = 0; e < 16; ++e) acc[mi][nj][e] = 0.f;

#define STG_A(kt_) do { const int b_ = (kt_) & 3; const int ko_ = (kt_) * 32; \
    async16(aS0 + ko_, &As[b_][d0]); async16(aS1 + ko_, &As[b_][d1]); } while (0)

  const int NT = K >> 5;
  // prologue: A tiles 0,1 in flight; retire tile 0 (tile 1's 2 stay out)
  STG_A(0); STG_A(1);
  asm volatile("s_waitcnt vmcnt(2)" ::: "memory");
  asm volatile("s_barrier" ::: "memory");

  for (int kt = 0; kt < NT; ++kt) {
    const int bi = kt & 3;
    const unsigned short* as_ = As[bi];
    const int ko = kt * 32;

    // B-frags: direct per-lane global loads (L2-hot); compiler tracks deps
    bf16x8 bfv[2][2];
    bfv[0][0] = *(const bf16x8*)(bB0 + ko);
    bfv[0][1] = *(const bf16x8*)(bB0 + ko + 16);
    bfv[1][0] = *(const bf16x8*)(bB1 + ko);
    bfv[1][1] = *(const bf16x8*)(bB1 + ko + 16);

    // A-frags from LDS
    bf16x8 af[4][2];
#pragma unroll
    for (int mi = 0; mi < 4; ++mi) {
      af[mi][0] = *(const bf16x8*)(as_ + prA[mi] + pg0);
      af[mi][1] = *(const bf16x8*)(as_ + prA[mi] + pg1);
    }

    // stage A tile kt+2 AFTER the B loads (keeps them newest in the queue)
    if (kt + 2 < NT) { STG_A(kt + 2); }

#pragma unroll
    for (int mi = 0; mi < 4; ++mi)
#pragma unroll
      for (int nj = 0; nj < 2; ++nj) {
        acc[mi][nj] = __builtin_amdgcn_mfma_f32_32x32x16_bf16(af[mi][0], bfv[nj][0], acc[mi][nj], 0, 0, 0);
        acc[mi][nj] = __builtin_amdgcn_mfma_f32_32x32x16_bf16(af[mi][1], bfv[nj][1], acc[mi][nj], 0, 0, 0);
      }

    // retire stageA(kt+1) (and any straggler B); keep stageA(kt+2) in flight
    if (kt + 2 < NT) {
      asm volatile("s_waitcnt vmcnt(2)" ::: "memory");
    } else if (kt + 1 < NT) {
      asm volatile("s_waitcnt vmcnt(0)" ::: "memory");
    }
    asm volatile("s_barrier" ::: "memory");
  }
#undef STG_A

  // epilogue: col = l31, row = (reg&3) + 8*(reg>>2) + 4*lhi
#pragma unroll
  for (int mi = 0; mi < 4; ++mi) {
#pragma unroll
    for (int nj = 0; nj < 2; ++nj) {
      int gc = bn0 + wn + nj * 32 + l31;
      float bsv = bias[gc];
#pragma unroll
      for (int reg = 0; reg < 16; ++reg) {
        int gr = bm0 + wm + mi * 32 + (reg & 3) + 8 * (reg >> 2) + 4 * lhi;
        C[(size_t)gr * N + gc] = f2b(acc[mi][nj][reg] + bsv);
      }
    }
  }
}

// ------------- 128x128 R3-structure GEMM (final projection) -----------------
// Same verified loop skeleton (ring-4 BK=32, pair-row swizzle, 1 barrier per
// K-tile, counted vmcnt(4)) at 128x128 / 4 waves / 64 KiB LDS -> 2 blocks/CU.
__global__ __launch_bounds__(256, 2) void gemm128(
    const unsigned short* __restrict__ A, const unsigned short* __restrict__ Bt,
    const float* __restrict__ bias, float* __restrict__ C,
    int M, int N, int K) {
  __shared__ __align__(16) unsigned short As[4][4096];
  __shared__ __align__(16) unsigned short Bs[4][4096];
  const int t = threadIdx.x;
  const int lane = t & 63, w = t >> 6;
  const int l31 = lane & 31, lhi = lane >> 5;
  const int wm = (w >> 1) * 64, wn = (w & 1) * 64;
  const int bm0 = blockIdx.y * 128, bn0 = blockIdx.x * 128;

  const int p0 = t & 7, pr0 = t >> 3;
  const int u0 = p0 ^ (pr0 & 7);
  const size_t aoff0 = (size_t)(2 * pr0 + (u0 & 1)) * K + (u0 >> 1) * 8;
  const unsigned short* aS0 = A + (size_t)bm0 * K + aoff0;
  const unsigned short* aS1 = aS0 + (size_t)64 * K;
  const unsigned short* bS0 = Bt + (size_t)bn0 * K + aoff0;
  const unsigned short* bS1 = bS0 + (size_t)64 * K;
  const int d0 = t * 8, d1 = d0 + 2048;

  const int plo = 2 * lhi + (l31 & 1);
  const int pswz = (l31 >> 1) & 7;
  const int pg0 = ((0 + plo) ^ pswz) * 8;
  const int pg1 = ((4 + plo) ^ pswz) * 8;
  int prA[2], prB[2];
#pragma unroll
  for (int mi = 0; mi < 2; ++mi) prA[mi] = ((wm + mi * 32 + l31) >> 1) * 64;
#pragma unroll
  for (int nj = 0; nj < 2; ++nj) prB[nj] = ((wn + nj * 32 + l31) >> 1) * 64;

  f32x16 acc[2][2];
#pragma unroll
  for (int mi = 0; mi < 2; ++mi)
#pragma unroll
    for (int nj = 0; nj < 2; ++nj)
#pragma unroll
      for (int e = 0; e < 16; ++e) acc[mi][nj][e] = 0.f;

#define STG_A(kt_) do { const int b_ = (kt_) & 3; const int ko_ = (kt_) * 32; \
    async16(aS0 + ko_, &As[b_][d0]); async16(aS1 + ko_, &As[b_][d1]); } while (0)
#define STG_B(kt_) do { const int b_ = (kt_) & 3; const int ko_ = (kt_) * 32; \
    async16(bS0 + ko_, &Bs[b_][d0]); async16(bS1 + ko_, &Bs[b_][d1]); } while (0)

  const int NT = K >> 5;
  STG_A(0); STG_B(0); STG_A(1); STG_B(1);
  asm volatile("s_waitcnt vmcnt(4)" ::: "memory");
  asm volatile("s_barrier" ::: "memory");

  for (int kt = 0; kt < NT; ++kt) {
    const int bi = kt & 3;
    const unsigned short* as_ = As[bi];
    const unsigned short* bs_ = Bs[bi];

    bf16x8 af[2][2], bfv[2][2];
#pragma unroll
    for (int mi = 0; mi < 2; ++mi) {
      af[mi][0] = *(const bf16x8*)(as_ + prA[mi] + pg0);
      af[mi][1] = *(const bf16x8*)(as_ + prA[mi] + pg1);
    }
#pragma unroll
    for (int nj = 0; nj < 2; ++nj) {
      bfv[nj][0] = *(const bf16x8*)(bs_ + prB[nj] + pg0);
      bfv[nj][1] = *(const bf16x8*)(bs_ + prB[nj] + pg1);
    }
    if (kt + 2 < NT) { STG_A(kt + 2); STG_B(kt + 2); }

#pragma unroll
    for (int mi = 0; mi < 2; ++mi)
#pragma unroll
      for (int nj = 0; nj < 2; ++nj) {
        acc[mi][nj] = __builtin_amdgcn_mfma_f32_32x32x16_bf16(af[mi][0], bfv[nj][0], acc[mi][nj], 0, 0, 0);
        acc[mi][nj] = __builtin_amdgcn_mfma_f32_32x32x16_bf16(af[mi][1], bfv[nj][1], acc[mi][nj], 0, 0, 0);
      }

    if (kt + 2 < NT) {
      asm volatile("s_waitcnt vmcnt(4)" ::: "memory");
    } else if (kt + 1 < NT) {
      asm volatile("s_waitcnt vmcnt(0)" ::: "memory");
    }
    asm volatile("s_barrier" ::: "memory");
  }
#undef STG_A
#undef STG_B

#pragma unroll
  for (int mi = 0; mi < 2; ++mi) {
#pragma unroll
    for (int nj = 0; nj < 2; ++nj) {
      int gc = bn0 + wn + nj * 32 + l31;
      float bsv = bias[gc];
#pragma unroll
      for (int reg = 0; reg < 16; ++reg) {
        int gr = bm0 + wm + mi * 32 + (reg & 3) + 8 * (reg >> 2) + 4 * lhi;
        C[(size_t)gr * N + gc] = acc[mi][nj][reg] + bsv;
      }
    }
  }
}

// ------------------- per-position head-softmax attention --------------------
// P stride 20 (float4-aligned, <=2-way aliasing = free), b128 pf gather, rcp.
__global__ __launch_bounds__(256) void attn_scatter(const unsigned short* __restrict__ qkv,
                                                    unsigned short* __restrict__ t) {
  __shared__ __align__(16) unsigned short vs[4][1024];
  __shared__ __align__(16) float ps[4][16 * 20];
  const int w = threadIdx.x >> 6, lane = threadIdx.x & 63;
  const int pos = blockIdx.x * 4 + w;  // 0..8191
  const int b = pos >> 11, s = pos & 2047;
  const unsigned short* row = qkv + (size_t)pos * 6144;
  unsigned short* vw = vs[w];
  float* pw = ps[w];
  const int lr = lane & 15, lq = lane >> 4;

  {
    const uint4* sv = (const uint4*)(row + 5120);
    uint4* dv = (uint4*)vw;
    dv[lane * 2] = sv[lane * 2];
    dv[lane * 2 + 1] = sv[lane * 2 + 1];
  }
  bf16x8 kf0 = *(const bf16x8*)(row + 4096 + lr * 64 + lq * 8);
  bf16x8 kf1 = *(const bf16x8*)(row + 4096 + lr * 64 + 32 + lq * 8);

  bf16x8 vf[4];
#pragma unroll
  for (int dc = 0; dc < 4; ++dc) {
#pragma unroll
    for (int j = 0; j < 8; ++j) vf[dc][j] = (__bf16)0.0f;
    if (lq < 2) {
      const __bf16* vb = (const __bf16*)vw;
#pragma unroll
      for (int j = 0; j < 8; ++j)
        vf[dc][j] = vb[(lq * 8 + j) * 64 + dc * 16 + lr];
    }
  }

  f32x4 acc[4];
#pragma unroll
  for (int dc = 0; dc < 4; ++dc) acc[dc] = (f32x4){0.f, 0.f, 0.f, 0.f};

#pragma unroll
  for (int qi = 0; qi < 4; ++qi) {
    bf16x8 qf0 = *(const bf16x8*)(row + qi * 1024 + lr * 64 + lq * 8);
    bf16x8 qf1 = *(const bf16x8*)(row + qi * 1024 + lr * 64 + 32 + lq * 8);
    f32x4 sc = {0.f, 0.f, 0.f, 0.f};
    sc = __builtin_amdgcn_mfma_f32_16x16x32_bf16(qf0, kf0, sc, 0, 0, 0);
    sc = __builtin_amdgcn_mfma_f32_16x16x32_bf16(qf1, kf1, sc, 0, 0, 0);
#pragma unroll
    for (int r = 0; r < 4; ++r) {
      float e = __expf(sc[r] * 0.125f);  // scores bounded, max-sub unnecessary
      float sum = e;
#pragma unroll
      for (int d = 1; d < 16; d <<= 1) sum += __shfl_xor(sum, d);
      pw[(lq * 4 + r) * 20 + lr] = e * __builtin_amdgcn_rcpf(sum);
    }
    bf16x8 pf;
#pragma unroll
    for (int j = 0; j < 8; ++j) pf[j] = (__bf16)0.0f;
    if (lq < 2) {
      const float4* pp = (const float4*)(pw + lr * 20 + lq * 8);
      float4 pa = pp[0], pb = pp[1];
      pf[0] = (__bf16)pa.x; pf[1] = (__bf16)pa.y;
      pf[2] = (__bf16)pa.z; pf[3] = (__bf16)pa.w;
      pf[4] = (__bf16)pb.x; pf[5] = (__bf16)pb.y;
      pf[6] = (__bf16)pb.z; pf[7] = (__bf16)pb.w;
    }
#pragma unroll
    for (int dc = 0; dc < 4; ++dc)
      acc[dc] = __builtin_amdgcn_mfma_f32_16x16x32_bf16(vf[dc], pf, acc[dc], 0, 0, 0);
  }

  size_t base = ((size_t)(b * 2048 + 128 * lr + (s >> 4))) * 1024 + 64 * (s & 15) + lq * 4;
#pragma unroll
  for (int dc = 0; dc < 4; ++dc) {
    uint2 u;
    u.x = (unsigned)f2b(acc[dc][0]) | ((unsigned)f2b(acc[dc][1]) << 16);
    u.y = (unsigned)f2b(acc[dc][2]) | ((unsigned)f2b(acc[dc][3]) << 16);
    *(uint2*)(t + base + dc * 16) = u;
  }
}

// ---------------------------------------------------------------------------
extern "C" void kernel_launch(void* const* d_in, const int* in_sizes, int n_in,
                              void* d_out, int out_size, void* d_ws, size_t ws_size,
                              hipStream_t stream) {
  const float* x  = (const float*)d_in[0];
  const float* Wq = (const float*)d_in[1];
  const float* bq = (const float*)d_in[2];
  const float* Wk = (const float*)d_in[3];
  const float* bk = (const float*)d_in[4];
  const float* Wv = (const float*)d_in[5];
  const float* bv = (const float*)d_in[6];
  const float* Wo = (const float*)d_in[7];
  const float* bo = (const float*)d_in[8];
  float* out = (float*)d_out;

  char* ws = (char*)d_ws;
  unsigned short* xb      = (unsigned short*)(ws + 0);         // 8192x1024 bf16 (16MB); aliased as t later
  unsigned short* wcat    = (unsigned short*)(ws + 16777216);  // 6144x1024 bf16 (12MB): Wq|Wk|Wv
  unsigned short* wo_b    = (unsigned short*)(ws + 29360128);  // 1024x1024 bf16 (2MB)
  float*          biascat = (float*)(ws + 31457280);           // 6144 fp32
  unsigned short* qkv     = (unsigned short*)(ws + 31481856);  // 8192x6144 bf16 (96MB)
  unsigned short* t       = xb;  // safe alias: xb dead after QKV GEMM

  cvt_all<<<15384, 256, 0, stream>>>(x, Wq, Wk, Wv, Wo, bq, bk, bv, xb, wcat, wo_b, biascat);

  // QKV: (8192x1024) x (6144x1024)^T -> 8192x6144 bf16  (B direct from L2)
  gemm256<<<dim3(24, 32), 512, 0, stream>>>(xb, wcat, biascat, qkv, 8192, 6144, 1024);
  // attention + permute/sum scatter -> t (8192x1024 bf16)
  attn_scatter<<<2048, 256, 0, stream>>>(qkv, t);
  // final: t x Wo^T + bo -> fp32 out  (R3 structure @128^2, 2 blocks/CU)
  gemm128<<<dim3(8, 64), 256, 0, stream>>>(t, wo_b, bo, out, 8192, 1024, 1024);
}

// Round 11
// 262.869 us; speedup vs baseline: 1.2758x; 1.2758x over previous
//
#include <hip/hip_runtime.h>

// ---------------------------------------------------------------------------
// MultiQueryAttention: B=4 S=2048 E=1024 H=16 D=64 Q=4
// ref: q=x@Wq^T+bq (per qi), k=x@Wk^T+bk, v=x@Wv^T+bv
//      scores[qi,b,s,h,g] = dot_d(q[h],k[g])/8 ; softmax over g (16 heads!)
//      out[qi,b,s,h,d] = sum_g p*v[g,d]
//      t[b, 128h + s/16, 64(s%16)+d] = sum_qi out   (torch transpose+reshape)
//      final = t @ Wo^T + bo   (fp32 out)
// ---------------------------------------------------------------------------

typedef __bf16 bf16x8 __attribute__((ext_vector_type(8)));
typedef float f32x4 __attribute__((ext_vector_type(4)));
typedef float f32x16 __attribute__((ext_vector_type(16)));

__device__ __forceinline__ unsigned short f2b(float f) {
  unsigned u = __float_as_uint(f);
  return (unsigned short)((u + 0x7fffu + ((u >> 16) & 1u)) >> 16);  // RNE
}

__device__ __forceinline__ void async16(const void* g, void* l) {
  __builtin_amdgcn_global_load_lds(
      (const __attribute__((address_space(1))) void*)g,
      (__attribute__((address_space(3))) void*)l, 16, 0, 0);
}

// ------------------- fused fp32->bf16 convert + bias concat ------------------
__global__ __launch_bounds__(256) void cvt_all(
    const float* __restrict__ x, const float* __restrict__ Wq, const float* __restrict__ Wk,
    const float* __restrict__ Wv, const float* __restrict__ Wo, const float* __restrict__ bq,
    const float* __restrict__ bk, const float* __restrict__ bv,
    unsigned short* __restrict__ xb, unsigned short* __restrict__ wcat,
    unsigned short* __restrict__ wo_b, float* __restrict__ biascat) {
  if (blockIdx.x >= 15360) {
    int j = (blockIdx.x - 15360) * 256 + threadIdx.x;  // 0..6143
    if (j < 6144) {
      float v = (j < 4096) ? bq[j] : (j < 5120 ? bk[j - 4096] : bv[j - 5120]);
      biascat[j] = v;
    }
    return;
  }
  int i = blockIdx.x * 256 + threadIdx.x;
  const float* s;
  unsigned short* d;
  int off;
  if (i < 2097152)      { s = x;  d = xb;             off = i; }
  else if (i < 3145728) { s = Wq; d = wcat;           off = i - 2097152; }
  else if (i < 3407872) { s = Wk; d = wcat + 4194304; off = i - 3145728; }
  else if (i < 3670016) { s = Wv; d = wcat + 5242880; off = i - 3407872; }
  else                  { s = Wo; d = wo_b;           off = i - 3670016; }
  float4 v = ((const float4*)s)[off];
  uint2 o;
  o.x = (unsigned)f2b(v.x) | ((unsigned)f2b(v.y) << 16);
  o.y = (unsigned)f2b(v.z) | ((unsigned)f2b(v.w) << 16);
  ((uint2*)d)[off] = o;
}

// ------------------ 256x256 deep-pipelined GEMM (QKV) -----------------------
// R3/R9 EXACT — verified local optimum (114-116us, MfmaUtil 39%, 0 conflicts;
// reproduced twice). Ledger of reverted attempts: R4 dist-2 prefetch (151us),
// R5 setprio (130us; 1 block/CU), R6 consumption-order (144us), R2/R8
// 8-phase (140/132us), R10 B-direct-from-L2 (195us; uncoalesced 16B loads).
// DO NOT MODIFY without a within-probe A/B.
__global__ __launch_bounds__(512, 2) void gemm256(
    const unsigned short* __restrict__ A, const unsigned short* __restrict__ Bt,
    const float* __restrict__ bias, unsigned short* __restrict__ C,
    int M, int N, int K) {
  __shared__ __align__(16) unsigned short As[4][8192];
  __shared__ __align__(16) unsigned short Bs[4][8192];
  const int t = threadIdx.x;
  const int lane = t & 63, w = t >> 6;
  const int l31 = lane & 31, lhi = lane >> 5;
  const int wm = (w >> 2) * 128, wn = (w & 3) * 64;
  const int bm0 = blockIdx.y * 256, bn0 = blockIdx.x * 256;

  const int p0 = t & 7, pr0 = t >> 3;
  const int u0 = p0 ^ (pr0 & 7);
  const size_t aoff0 = (size_t)(2 * pr0 + (u0 & 1)) * K + (u0 >> 1) * 8;
  const unsigned short* aS0 = A + (size_t)bm0 * K + aoff0;
  const unsigned short* aS1 = aS0 + (size_t)128 * K;
  const unsigned short* bS0 = Bt + (size_t)bn0 * K + aoff0;
  const unsigned short* bS1 = bS0 + (size_t)128 * K;
  const int d0 = t * 8, d1 = d0 + 4096;

  const int plo = 2 * lhi + (l31 & 1);
  const int pswz = (l31 >> 1) & 7;
  const int pg0 = ((0 + plo) ^ pswz) * 8;
  const int pg1 = ((4 + plo) ^ pswz) * 8;
  int prA[4], prB[2];
#pragma unroll
  for (int mi = 0; mi < 4; ++mi) prA[mi] = ((wm + mi * 32 + l31) >> 1) * 64;
#pragma unroll
  for (int nj = 0; nj < 2; ++nj) prB[nj] = ((wn + nj * 32 + l31) >> 1) * 64;

  f32x16 acc[4][2];
#pragma unroll
  for (int mi = 0; mi < 4; ++mi)
#pragma unroll
    for (int nj = 0; nj < 2; ++nj)
#pragma unroll
      for (int e = 0; e < 16; ++e) acc[mi][nj][e] = 0.f;

#define STG_A(kt_) do { const int b_ = (kt_) & 3; const int ko_ = (kt_) * 32; \
    async16(aS0 + ko_, &As[b_][d0]); async16(aS1 + ko_, &As[b_][d1]); } while (0)
#define STG_B(kt_) do { const int b_ = (kt_) & 3; const int ko_ = (kt_) * 32; \
    async16(bS0 + ko_, &Bs[b_][d0]); async16(bS1 + ko_, &Bs[b_][d1]); } while (0)

  const int NT = K >> 5;
  STG_A(0); STG_B(0); STG_A(1); STG_B(1);
  asm volatile("s_waitcnt vmcnt(4)" ::: "memory");
  asm volatile("s_barrier" ::: "memory");

  for (int kt = 0; kt < NT; ++kt) {
    const int bi = kt & 3;
    const unsigned short* as_ = As[bi];
    const unsigned short* bs_ = Bs[bi];

    bf16x8 af[4][2], bfv[2][2];
#pragma unroll
    for (int mi = 0; mi < 4; ++mi) {
      af[mi][0] = *(const bf16x8*)(as_ + prA[mi] + pg0);
      af[mi][1] = *(const bf16x8*)(as_ + prA[mi] + pg1);
    }
#pragma unroll
    for (int nj = 0; nj < 2; ++nj) {
      bfv[nj][0] = *(const bf16x8*)(bs_ + prB[nj] + pg0);
      bfv[nj][1] = *(const bf16x8*)(bs_ + prB[nj] + pg1);
    }
    if (kt + 2 < NT) { STG_A(kt + 2); STG_B(kt + 2); }

#pragma unroll
    for (int mi = 0; mi < 4; ++mi)
#pragma unroll
      for (int nj = 0; nj < 2; ++nj) {
        acc[mi][nj] = __builtin_amdgcn_mfma_f32_32x32x16_bf16(af[mi][0], bfv[nj][0], acc[mi][nj], 0, 0, 0);
        acc[mi][nj] = __builtin_amdgcn_mfma_f32_32x32x16_bf16(af[mi][1], bfv[nj][1], acc[mi][nj], 0, 0, 0);
      }

    if (kt + 2 < NT) {
      asm volatile("s_waitcnt vmcnt(4)" ::: "memory");
    } else if (kt + 1 < NT) {
      asm volatile("s_waitcnt vmcnt(0)" ::: "memory");
    }
    asm volatile("s_barrier" ::: "memory");
  }
#undef STG_A
#undef STG_B

#pragma unroll
  for (int mi = 0; mi < 4; ++mi) {
#pragma unroll
    for (int nj = 0; nj < 2; ++nj) {
      int gc = bn0 + wn + nj * 32 + l31;
      float bsv = bias[gc];
#pragma unroll
      for (int reg = 0; reg < 16; ++reg) {
        int gr = bm0 + wm + mi * 32 + (reg & 3) + 8 * (reg >> 2) + 4 * lhi;
        C[(size_t)gr * N + gc] = f2b(acc[mi][nj][reg] + bsv);
      }
    }
  }
}

// ------------- 128x128 R3-structure GEMM (final projection) -----------------
// R9 exact: ring-4 BK=32, pair-row swizzle, 1 barrier/K-tile, counted
// vmcnt(4); 4 waves / 64 KiB LDS -> 2 blocks/CU. fp32 out.
__global__ __launch_bounds__(256, 2) void gemm128(
    const unsigned short* __restrict__ A, const unsigned short* __restrict__ Bt,
    const float* __restrict__ bias, float* __restrict__ C,
    int M, int N, int K) {
  __shared__ __align__(16) unsigned short As[4][4096];
  __shared__ __align__(16) unsigned short Bs[4][4096];
  const int t = threadIdx.x;
  const int lane = t & 63, w = t >> 6;
  const int l31 = lane & 31, lhi = lane >> 5;
  const int wm = (w >> 1) * 64, wn = (w & 1) * 64;
  const int bm0 = blockIdx.y * 128, bn0 = blockIdx.x * 128;

  const int p0 = t & 7, pr0 = t >> 3;
  const int u0 = p0 ^ (pr0 & 7);
  const size_t aoff0 = (size_t)(2 * pr0 + (u0 & 1)) * K + (u0 >> 1) * 8;
  const unsigned short* aS0 = A + (size_t)bm0 * K + aoff0;
  const unsigned short* aS1 = aS0 + (size_t)64 * K;
  const unsigned short* bS0 = Bt + (size_t)bn0 * K + aoff0;
  const unsigned short* bS1 = bS0 + (size_t)64 * K;
  const int d0 = t * 8, d1 = d0 + 2048;

  const int plo = 2 * lhi + (l31 & 1);
  const int pswz = (l31 >> 1) & 7;
  const int pg0 = ((0 + plo) ^ pswz) * 8;
  const int pg1 = ((4 + plo) ^ pswz) * 8;
  int prA[2], prB[2];
#pragma unroll
  for (int mi = 0; mi < 2; ++mi) prA[mi] = ((wm + mi * 32 + l31) >> 1) * 64;
#pragma unroll
  for (int nj = 0; nj < 2; ++nj) prB[nj] = ((wn + nj * 32 + l31) >> 1) * 64;

  f32x16 acc[2][2];
#pragma unroll
  for (int mi = 0; mi < 2; ++mi)
#pragma unroll
    for (int nj = 0; nj < 2; ++nj)
#pragma unroll
      for (int e = 0; e < 16; ++e) acc[mi][nj][e] = 0.f;

#define STG_A(kt_) do { const int b_ = (kt_) & 3; const int ko_ = (kt_) * 32; \
    async16(aS0 + ko_, &As[b_][d0]); async16(aS1 + ko_, &As[b_][d1]); } while (0)
#define STG_B(kt_) do { const int b_ = (kt_) & 3; const int ko_ = (kt_) * 32; \
    async16(bS0 + ko_, &Bs[b_][d0]); async16(bS1 + ko_, &Bs[b_][d1]); } while (0)

  const int NT = K >> 5;
  STG_A(0); STG_B(0); STG_A(1); STG_B(1);
  asm volatile("s_waitcnt vmcnt(4)" ::: "memory");
  asm volatile("s_barrier" ::: "memory");

  for (int kt = 0; kt < NT; ++kt) {
    const int bi = kt & 3;
    const unsigned short* as_ = As[bi];
    const unsigned short* bs_ = Bs[bi];

    bf16x8 af[2][2], bfv[2][2];
#pragma unroll
    for (int mi = 0; mi < 2; ++mi) {
      af[mi][0] = *(const bf16x8*)(as_ + prA[mi] + pg0);
      af[mi][1] = *(const bf16x8*)(as_ + prA[mi] + pg1);
    }
#pragma unroll
    for (int nj = 0; nj < 2; ++nj) {
      bfv[nj][0] = *(const bf16x8*)(bs_ + prB[nj] + pg0);
      bfv[nj][1] = *(const bf16x8*)(bs_ + prB[nj] + pg1);
    }
    if (kt + 2 < NT) { STG_A(kt + 2); STG_B(kt + 2); }

#pragma unroll
    for (int mi = 0; mi < 2; ++mi)
#pragma unroll
      for (int nj = 0; nj < 2; ++nj) {
        acc[mi][nj] = __builtin_amdgcn_mfma_f32_32x32x16_bf16(af[mi][0], bfv[nj][0], acc[mi][nj], 0, 0, 0);
        acc[mi][nj] = __builtin_amdgcn_mfma_f32_32x32x16_bf16(af[mi][1], bfv[nj][1], acc[mi][nj], 0, 0, 0);
      }

    if (kt + 2 < NT) {
      asm volatile("s_waitcnt vmcnt(4)" ::: "memory");
    } else if (kt + 1 < NT) {
      asm volatile("s_waitcnt vmcnt(0)" ::: "memory");
    }
    asm volatile("s_barrier" ::: "memory");
  }
#undef STG_A
#undef STG_B

#pragma unroll
  for (int mi = 0; mi < 2; ++mi) {
#pragma unroll
    for (int nj = 0; nj < 2; ++nj) {
      int gc = bn0 + wn + nj * 32 + l31;
      float bsv = bias[gc];
#pragma unroll
      for (int reg = 0; reg < 16; ++reg) {
        int gr = bm0 + wm + mi * 32 + (reg & 3) + 8 * (reg >> 2) + 4 * lhi;
        C[(size_t)gr * N + gc] = acc[mi][nj][reg] + bsv;
      }
    }
  }
}

// ------------------- per-position head-softmax attention --------------------
// R11: COALESCED OUTPUT. Old epilogue scattered 8B stores at 256KB strides
// (32B-useful per 64B line on 16MB of writes). The block's 4 positions share
// b and s>>4, so its output forms 16 rows x 512B CONTIGUOUS spans. New:
// stage per-wave output into the dead vs[] buffer (V-frags already in regs),
// one barrier, then 512 coalesced 16B stores per block. LDS XOR
// (colb ^ ((row&7)<<4) ^ (wave<<5)) keeps store bursts at the 4-way floor
// for 8B ops (m136: inherent minimum for wave64 x 8B).
__global__ __launch_bounds__(256) void attn_scatter(const unsigned short* __restrict__ qkv,
                                                    unsigned short* __restrict__ t) {
  __shared__ __align__(16) unsigned short vs[4][1024];
  __shared__ __align__(16) float ps[4][16 * 20];
  const int w = threadIdx.x >> 6, lane = threadIdx.x & 63;
  const int pos = blockIdx.x * 4 + w;  // 0..8191
  const unsigned short* row = qkv + (size_t)pos * 6144;
  unsigned short* vw = vs[w];
  float* pw = ps[w];
  const int lr = lane & 15, lq = lane >> 4;

  {
    const uint4* sv = (const uint4*)(row + 5120);
    uint4* dv = (uint4*)vw;
    dv[lane * 2] = sv[lane * 2];
    dv[lane * 2 + 1] = sv[lane * 2 + 1];
  }
  bf16x8 kf0 = *(const bf16x8*)(row + 4096 + lr * 64 + lq * 8);
  bf16x8 kf1 = *(const bf16x8*)(row + 4096 + lr * 64 + 32 + lq * 8);

  bf16x8 vf[4];
#pragma unroll
  for (int dc = 0; dc < 4; ++dc) {
#pragma unroll
    for (int j = 0; j < 8; ++j) vf[dc][j] = (__bf16)0.0f;
    if (lq < 2) {
      const __bf16* vb = (const __bf16*)vw;
#pragma unroll
      for (int j = 0; j < 8; ++j)
        vf[dc][j] = vb[(lq * 8 + j) * 64 + dc * 16 + lr];
    }
  }

  f32x4 acc[4];
#pragma unroll
  for (int dc = 0; dc < 4; ++dc) acc[dc] = (f32x4){0.f, 0.f, 0.f, 0.f};

#pragma unroll
  for (int qi = 0; qi < 4; ++qi) {
    bf16x8 qf0 = *(const bf16x8*)(row + qi * 1024 + lr * 64 + lq * 8);
    bf16x8 qf1 = *(const bf16x8*)(row + qi * 1024 + lr * 64 + 32 + lq * 8);
    f32x4 sc = {0.f, 0.f, 0.f, 0.f};
    sc = __builtin_amdgcn_mfma_f32_16x16x32_bf16(qf0, kf0, sc, 0, 0, 0);
    sc = __builtin_amdgcn_mfma_f32_16x16x32_bf16(qf1, kf1, sc, 0, 0, 0);
#pragma unroll
    for (int r = 0; r < 4; ++r) {
      float e = __expf(sc[r] * 0.125f);  // scores bounded, max-sub unnecessary
      float sum = e;
#pragma unroll
      for (int d = 1; d < 16; d <<= 1) sum += __shfl_xor(sum, d);
      pw[(lq * 4 + r) * 20 + lr] = e * __builtin_amdgcn_rcpf(sum);
    }
    bf16x8 pf;
#pragma unroll
    for (int j = 0; j < 8; ++j) pf[j] = (__bf16)0.0f;
    if (lq < 2) {
      const float4* pp = (const float4*)(pw + lr * 20 + lq * 8);
      float4 pa = pp[0], pb = pp[1];
      pf[0] = (__bf16)pa.x; pf[1] = (__bf16)pa.y;
      pf[2] = (__bf16)pa.z; pf[3] = (__bf16)pa.w;
      pf[4] = (__bf16)pb.x; pf[5] = (__bf16)pb.y;
      pf[6] = (__bf16)pb.z; pf[7] = (__bf16)pb.w;
    }
#pragma unroll
    for (int dc = 0; dc < 4; ++dc)
      acc[dc] = __builtin_amdgcn_mfma_f32_16x16x32_bf16(vf[dc], pf, acc[dc], 0, 0, 0);
  }

  // ---- stage out[h=lr][d=dc*16+lq*4+r] into vs[w] (V dead), XOR-spread ----
#pragma unroll
  for (int dc = 0; dc < 4; ++dc) {
    uint2 u;
    u.x = (unsigned)f2b(acc[dc][0]) | ((unsigned)f2b(acc[dc][1]) << 16);
    u.y = (unsigned)f2b(acc[dc][2]) | ((unsigned)f2b(acc[dc][3]) << 16);
    int colb = dc * 32 + lq * 8;                       // byte col 0..127
    int phys = colb ^ ((lr & 7) << 4) ^ (w << 5);      // 8B-align preserved
    *(uint2*)((char*)vw + lr * 128 + phys) = u;
  }
  __syncthreads();

  // ---- block-coop coalesced write: 16 rows x 512B contiguous spans ----
  const int pos0 = blockIdx.x * 4;
  const int b0 = pos0 >> 11, s0 = pos0 & 2047;
  const size_t rowbase = (size_t)(b0 * 2048 + (s0 >> 4)) * 1024 + 64 * (s0 & 15);
#pragma unroll
  for (int i = 0; i < 2; ++i) {
    int chunk = i * 256 + threadIdx.x;   // 0..511
    int h = chunk >> 5;                  // 0..15
    int c16 = chunk & 31;                // 16B unit within the 512B span
    int wi = c16 >> 3;                   // source position (wave)
    int dloc = (c16 & 7) * 8;            // d start
    int colb = dloc * 2;
    int phys = colb ^ ((h & 7) << 4) ^ (wi << 5);
    uint4 v = *(const uint4*)((const char*)vs[wi] + h * 128 + phys);
    *(uint4*)(t + rowbase + (size_t)h * 128 * 1024 + wi * 64 + dloc) = v;
  }
}

// ---------------------------------------------------------------------------
extern "C" void kernel_launch(void* const* d_in, const int* in_sizes, int n_in,
                              void* d_out, int out_size, void* d_ws, size_t ws_size,
                              hipStream_t stream) {
  const float* x  = (const float*)d_in[0];
  const float* Wq = (const float*)d_in[1];
  const float* bq = (const float*)d_in[2];
  const float* Wk = (const float*)d_in[3];
  const float* bk = (const float*)d_in[4];
  const float* Wv = (const float*)d_in[5];
  const float* bv = (const float*)d_in[6];
  const float* Wo = (const float*)d_in[7];
  const float* bo = (const float*)d_in[8];
  float* out = (float*)d_out;

  char* ws = (char*)d_ws;
  unsigned short* xb      = (unsigned short*)(ws + 0);         // 8192x1024 bf16 (16MB); aliased as t later
  unsigned short* wcat    = (unsigned short*)(ws + 16777216);  // 6144x1024 bf16 (12MB): Wq|Wk|Wv
  unsigned short* wo_b    = (unsigned short*)(ws + 29360128);  // 1024x1024 bf16 (2MB)
  float*          biascat = (float*)(ws + 31457280);           // 6144 fp32
  unsigned short* qkv     = (unsigned short*)(ws + 31481856);  // 8192x6144 bf16 (96MB)
  unsigned short* t       = xb;  // safe alias: xb dead after QKV GEMM

  cvt_all<<<15384, 256, 0, stream>>>(x, Wq, Wk, Wv, Wo, bq, bk, bv, xb, wcat, wo_b, biascat);

  // QKV: (8192x1024) x (6144x1024)^T -> 8192x6144 bf16  (R3 structure)
  gemm256<<<dim3(24, 32), 512, 0, stream>>>(xb, wcat, biascat, qkv, 8192, 6144, 1024);
  // attention + permute/sum scatter -> t (8192x1024 bf16), coalesced writes
  attn_scatter<<<2048, 256, 0, stream>>>(qkv, t);
  // final: t x Wo^T + bo -> fp32 out  (R3 structure @128^2, 2 blocks/CU)
  gemm128<<<dim3(8, 64), 256, 0, stream>>>(t, wo_b, bo, out, 8192, 1024, 1024);
}